// Round 3
// baseline (1222.962 us; speedup 1.0000x reference)
//
#include <hip/hip_runtime.h>
#include <cstdint>
#include <cstddef>
#include <type_traits>

// ---------------- problem constants ----------------
#define OUT_DIM    65
#define TREE_STRIDE 66
#define N_NODE     1023
#define N_INTN     511

typedef _Float16 f16;
typedef _Float16 f16x8 __attribute__((ext_vector_type(8)));
typedef _Float16 f16x4 __attribute__((ext_vector_type(4)));
typedef float    f32x4 __attribute__((ext_vector_type(4)));

template<int V> using ic = std::integral_constant<int, V>;

#define MFMA(a, b, c) __builtin_amdgcn_mfma_f32_16x16x32_f16((a), (b), (c), 0, 0, 0)

// counted wait with compile-time immediates; "memory" clobber pins issue order
// of surrounding loads (loads can't cross). MFMA correctness does NOT rely on
// this asm (data deps through compiler-visible loads) — it only pins schedule.
template<int VM, int LG>
__device__ __forceinline__ void waitcnt_t() {
  asm volatile("s_waitcnt vmcnt(%0) lgkmcnt(%1)" :: "n"(VM), "n"(LG) : "memory");
}

// H swizzle: elem(row,k) at row*512 + (((k>>3) ^ (row&15))<<3) + (k&7)
template<int MT>
__device__ __forceinline__ void storeH_fn(f16* __restrict__ H, f32x4 (&acc)[MT][4],
                                          const float* __restrict__ bias,
                                          int wcb, int quad, int l16) {
#pragma unroll
  for (int mt = 0; mt < MT; mt++) {
#pragma unroll
    for (int nt = 0; nt < 4; nt++) {
      const int c0 = wcb + nt * 16 + quad * 4;
      const float4 bv = *(const float4*)(bias + c0);
      f16x4 hv;
      float v0 = acc[mt][nt][0] + bv.x; hv[0] = (f16)(v0 > 0.f ? v0 : 0.f);
      float v1 = acc[mt][nt][1] + bv.y; hv[1] = (f16)(v1 > 0.f ? v1 : 0.f);
      float v2 = acc[mt][nt][2] + bv.z; hv[2] = (f16)(v2 > 0.f ? v2 : 0.f);
      float v3 = acc[mt][nt][3] + bv.w; hv[3] = (f16)(v3 > 0.f ? v3 : 0.f);
      const int row = mt * 16 + l16;
      *(f16x4*)&H[row * 512 + (((c0 >> 3) ^ l16) << 3) + (quad & 1) * 4] = hv;
    }
  }
}

// ---------------------------------------------------------------------------
// Barrier-free K-loop: B streamed global->VGPR in a depth-3 ring (prefetch
// distance 2), A via GetA (ds_read from stable LDS, or global for leaf l0).
// Per chunk C: issue B(C+2)+A(C+2) -> counted wait (vmcnt = NT*inflight,
// lgkmcnt = MT*inflight) -> MFMA on ring C%3. Ring-slot reuse is safe by
// in-order per-wave issue (slot consumed at step C, refilled at step C+1).
// No __syncthreads anywhere inside — waves drift freely (B is wave-private,
// A-source stable for the whole layer).
// ---------------------------------------------------------------------------
template<int NC, int MT, int NT, bool AGLOB, bool SWAP, typename GetB, typename GetA>
__device__ __forceinline__ void kloop(GetB getB, GetA getA, f32x4 (&acc)[MT][NT])
{
  f16x8 bs[3][NT];
  f16x8 as[3][MT];

#pragma unroll
  for (int nt = 0; nt < NT; nt++) bs[0][nt] = getB(0, nt);
#pragma unroll
  for (int mt = 0; mt < MT; mt++) as[0][mt] = getA(0, mt);
  if constexpr (NC > 1) {
#pragma unroll
    for (int nt = 0; nt < NT; nt++) bs[1][nt] = getB(1, nt);
#pragma unroll
    for (int mt = 0; mt < MT; mt++) as[1][mt] = getA(1, mt);
  }

  auto lp = [&](auto&& self, auto Cc) -> void {
    constexpr int C = decltype(Cc)::value;
    if constexpr (C < NC) {
      constexpr int RC = C % 3;
      if constexpr (C + 2 < NC) {
        constexpr int RI = (C + 2) % 3;
#pragma unroll
        for (int nt = 0; nt < NT; nt++) bs[RI][nt] = getB(C + 2, nt);
#pragma unroll
        for (int mt = 0; mt < MT; mt++) as[RI][mt] = getA(C + 2, mt);
      }
      constexpr int NR = (NC - 1 - C) < 2 ? (NC - 1 - C) : 2;  // chunks still in flight
      if constexpr (AGLOB) waitcnt_t<0, 0>();                  // A-globals pollute vmcnt
      else                 waitcnt_t<NT * NR, MT * NR>();
      __builtin_amdgcn_s_setprio(1);
#pragma unroll
      for (int mt = 0; mt < MT; mt++)
#pragma unroll
        for (int nt = 0; nt < NT; nt++)
          acc[mt][nt] = SWAP ? MFMA(bs[RC][nt], as[RC][mt], acc[mt][nt])
                             : MFMA(as[RC][mt], bs[RC][nt], acc[mt][nt]);
      __builtin_amdgcn_s_setprio(0);
      self(self, ic<C + 1>{});
    }
  };
  lp(lp, ic<0>{});
}

// one 512-col layer; B direct from global (wave-exclusive cols), 2 barriers
// total (around storeH). SWAP-operand MFMA: out row=l16, col=quad*4+r.
template<int K, bool AGLOB, typename GetA>
__device__ __forceinline__ void run_layer(
    const f16* __restrict__ Wt, const float* __restrict__ bias,
    f16* __restrict__ H, int wave, int quad, int l16, GetA getA)
{
  constexpr int NC = K / 32;
  const int wcb = wave * 64;
  const f16* bp[4];
#pragma unroll
  for (int nt = 0; nt < 4; nt++)
    bp[nt] = Wt + (long)(wcb + nt * 16 + l16) * K + quad * 8;
  auto getB = [&](int c, int nt) -> f16x8 {
    return *(const f16x8*)(bp[nt] + c * 32);
  };
  f32x4 acc[4][4];
#pragma unroll
  for (int i = 0; i < 4; i++)
#pragma unroll
    for (int j = 0; j < 4; j++) acc[i][j] = f32x4{0.f, 0.f, 0.f, 0.f};

  kloop<NC, 4, 4, AGLOB, true>(getB, getA, acc);

  __syncthreads();                 // all H/X reads of this layer done
  storeH_fn<4>(H, acc, bias, wcb, quad, l16);
  __syncthreads();                 // H visible for next layer
}

// ---------------- fused 4-layer MLP, 64 rows/block, 512 thr, any level ------
// LDS: H 64KB only. X[64][232] (internal layer-0 input) ALIASES H — safe:
// storeH(l0) writes H only after the barrier when all X reads are done.
__global__ __launch_bounds__(512, 2) void fused_mlp(
    const float* __restrict__ feats,
    const f16* __restrict__ w0t, const float* __restrict__ b0,
    const f16* __restrict__ w1t, const float* __restrict__ b1,
    const f16* __restrict__ w2t, const float* __restrict__ b2,
    const f16* __restrict__ wot, const float* __restrict__ bo,
    f16* __restrict__ tree, float* __restrict__ dOut, int lvl, int leaf)
{
  extern __shared__ f16 S[];
  f16* H = S;            // 32768 f16
  f16* X = S;            // [64][232] (internal l0 only; alias of H)

  const int tid  = threadIdx.x;
  const int wave = tid >> 6;
  const int lane = tid & 63;
  const int quad = lane >> 4;
  const int l16  = lane & 15;
  const long rowBase = (long)blockIdx.x * 64;

  if (!leaf) {
    // per-row (batch,node) mapping — valid even when a block spans batch
    // elements (lvl < 6). X row stride 232 f16 (=> balanced banks on b128).
    for (int i = tid; i < 4096; i += 512) {        // feats: 64 rows x 64
      int r = i >> 6, cc = i & 63;
      long rg = rowBase + r;
      long bbr = rg >> lvl;
      long ii = rg - (bbr << lvl);
      long nn = (1L << lvl) - 1 + ii;
      X[r * 232 + cc] = (f16)feats[(bbr * N_INTN + nn) * 64 + cc];
    }
    for (int i = tid; i < 8448; i += 512) {        // children: 64 rows x 132
      int r = i / 132, cc = i - r * 132;
      long rg = rowBase + r;
      long bbr = rg >> lvl;
      long ii = rg - (bbr << lvl);
      long nn = (1L << lvl) - 1 + ii;
      const f16* src = tree + (bbr * N_NODE + 2 * nn + 1) * TREE_STRIDE;
      // skip tree col 65 (uninitialized pad): left col j -> k=64+j,
      // right col j (at src[66+j]) -> k=129+j. No overlapping writes.
      int dst = (cc < 66) ? (cc == 65 ? -1 : 64 + cc)
                          : (cc == 131 ? -1 : 63 + cc);
      if (dst >= 0) X[r * 232 + dst] = src[cc];
    }
    for (int i = tid; i < 2432; i += 512) {        // zero k=194..231
      int r = i / 38, cc = i - r * 38;
      X[r * 232 + 194 + cc] = (f16)0.f;
    }
    __syncthreads();
  }

  // ---- layer 0 ----
  if (leaf) {
    auto gA = [&](int c, int mt) -> f16x8 {
      const float4* p = (const float4*)(feats + (rowBase + mt * 16 + l16) * 64 + c * 32 + quad * 8);
      float4 u0 = p[0], u1 = p[1];
      f16x8 a;
      a[0] = (f16)u0.x; a[1] = (f16)u0.y; a[2] = (f16)u0.z; a[3] = (f16)u0.w;
      a[4] = (f16)u1.x; a[5] = (f16)u1.y; a[6] = (f16)u1.z; a[7] = (f16)u1.w;
      return a;
    };
    run_layer<64, true>(w0t, b0, H, wave, quad, l16, gA);
  } else {
    auto gA = [&](int c, int mt) -> f16x8 {
      int row = mt * 16 + l16;
      return *(const f16x8*)&X[row * 232 + c * 32 + quad * 8];  // max 223 < 232
    };
    run_layer<224, false>(w0t, b0, H, wave, quad, l16, gA);
  }

  // ---- mid layers (A from H) ----
  auto getAH = [&](int c, int mt) -> f16x8 {
    int row = mt * 16 + l16;
    return *(const f16x8*)&H[row * 512 + ((((c * 4 + quad) ^ l16) << 3))];
  };
  run_layer<512, false>(w1t, b1, H, wave, quad, l16, getAH);
  run_layer<512, false>(w2t, b2, H, wave, quad, l16, getAH);

  // ---- out layer (512 -> 65), waves 0..3, B direct from global ----
  if (wave < 4) {
    const f16* bp[5];
#pragma unroll
    for (int nt = 0; nt < 5; nt++)
      bp[nt] = wot + (long)(nt * 16 + l16) * 512 + quad * 8;
    auto gB = [&](int c, int nt) -> f16x8 {
      return *(const f16x8*)(bp[nt] + c * 32);
    };
    const int orow = wave * 16 + l16;
    auto gA = [&](int c, int mt) -> f16x8 {
      return *(const f16x8*)&H[orow * 512 + ((((c * 4 + quad) ^ l16) << 3))];
    };
    f32x4 oacc[1][5];
#pragma unroll
    for (int i = 0; i < 5; i++) oacc[0][i] = f32x4{0.f, 0.f, 0.f, 0.f};

    kloop<16, 1, 5, false, false>(gB, gA, oacc);   // normal: row=quad*4+r, col=nt*16+l16

#pragma unroll
    for (int nt = 0; nt < 5; nt++)
#pragma unroll
      for (int r = 0; r < 4; r++) {
        int col = nt * 16 + l16;
        if (col < OUT_DIM) {
          long rg = rowBase + wave * 16 + quad * 4 + r;
          float v = oacc[0][nt][r] + bo[col];
          long b2_ = rg >> lvl;
          long ii  = rg - (b2_ << lvl);
          long node = (1L << lvl) - 1 + ii;
          tree[(b2_ * N_NODE + node) * TREE_STRIDE + col] = (f16)v;
          if (lvl == 0 && col == 0) dOut[rg] = v;   // lvl 0: rg = batch index
        }
      }
  }
}

// ---------------- merged weight transpose+cast ----------------
struct WSeg { const float* W; f16* Wt; int K, N, Kpad, start; };
struct WPack { WSeg s[8]; int total; };

__global__ void wcast_all(WPack p) {
  int idx = blockIdx.x * 256 + threadIdx.x;
  if (idx >= p.total) return;
  int si = 0;
#pragma unroll
  for (int i = 1; i < 8; i++) if (idx >= p.s[i].start) si = i;
  WSeg sg = p.s[si];
  int e = idx - sg.start;
  int n = e / sg.Kpad, k = e - n * sg.Kpad;
  float v = (n < sg.N && k < sg.K) ? sg.W[(long)k * sg.N + n] : 0.f;
  sg.Wt[e] = (f16)v;
}

// ---------------- host orchestration ----------------
extern "C" void kernel_launch(void* const* d_in, const int* in_sizes, int n_in,
                              void* d_out, int out_size, void* d_ws, size_t ws_size,
                              hipStream_t stream) {
  const float* leaf_feats     = (const float*)d_in[0];
  const float* internal_feats = (const float*)d_in[1];
  const float* lw0 = (const float*)d_in[2];
  const float* lb0 = (const float*)d_in[3];
  const float* lw1 = (const float*)d_in[4];
  const float* lb1 = (const float*)d_in[5];
  const float* lw2 = (const float*)d_in[6];
  const float* lb2 = (const float*)d_in[7];
  const float* lwo = (const float*)d_in[8];
  const float* lbo = (const float*)d_in[9];
  const float* iw0 = (const float*)d_in[10];
  const float* ib0 = (const float*)d_in[11];
  const float* iw1 = (const float*)d_in[12];
  const float* ib1 = (const float*)d_in[13];
  const float* iw2 = (const float*)d_in[14];
  const float* ib2 = (const float*)d_in[15];
  const float* iwo = (const float*)d_in[16];
  const float* ibo = (const float*)d_in[17];
  float* dOut = (float*)d_out;

  char* ws = (char*)d_ws;
  size_t off = 0;
  auto alloc = [&](size_t bytes) -> void* {
    void* p = ws + off;
    off += (bytes + 255) & ~(size_t)255;
    return p;
  };

  f16* lw0t = (f16*)alloc((size_t)512 * 64 * 2);
  f16* lw1t = (f16*)alloc((size_t)512 * 512 * 2);
  f16* lw2t = (f16*)alloc((size_t)512 * 512 * 2);
  f16* lwot = (f16*)alloc((size_t)128 * 512 * 2);
  f16* iw0t = (f16*)alloc((size_t)512 * 224 * 2);
  f16* iw1t = (f16*)alloc((size_t)512 * 512 * 2);
  f16* iw2t = (f16*)alloc((size_t)512 * 512 * 2);
  f16* iwot = (f16*)alloc((size_t)128 * 512 * 2);
  f16* tree = (f16*)alloc((size_t)256 * N_NODE * TREE_STRIDE * 2);

  WPack p;
  int cum = 0;
  auto seg = [&](int i, const float* W, f16* Wt, int K, int N, int Kpad, int Npad) {
    p.s[i] = {W, Wt, K, N, Kpad, cum};
    cum += Kpad * Npad;
  };
  seg(0, lw0, lw0t, 64, 512, 64, 512);
  seg(1, lw1, lw1t, 512, 512, 512, 512);
  seg(2, lw2, lw2t, 512, 512, 512, 512);
  seg(3, lwo, lwot, 512, 65, 512, 128);
  seg(4, iw0, iw0t, 194, 512, 224, 512);
  seg(5, iw1, iw1t, 512, 512, 512, 512);
  seg(6, iw2, iw2t, 512, 512, 512, 512);
  seg(7, iwo, iwot, 512, 65, 512, 128);
  p.total = cum;
  wcast_all<<<dim3((cum + 255) / 256), dim3(256), 0, stream>>>(p);

  static bool attrSet = false;
  if (!attrSet) {
    hipFuncSetAttribute(reinterpret_cast<const void*>(fused_mlp),
                        hipFuncAttributeMaxDynamicSharedMemorySize, 65536);
    attrSet = true;
  }

  const size_t shmem = 65536;   // H 64KB (X aliased)

  // leaf pass: 131072 rows -> nodes 511..1022
  fused_mlp<<<dim3(2048), dim3(512), shmem, stream>>>(
      leaf_feats, lw0t, lb0, lw1t, lb1, lw2t, lb2, lwot, lbo, tree, dOut, 9, 1);

  // internal levels 8..0 (grid = rows/64 = 4<<l; weights stay L2-hot)
  for (int l = 8; l >= 0; l--) {
    fused_mlp<<<dim3(4u << l), dim3(512), shmem, stream>>>(
        internal_feats, iw0t, ib0, iw1t, ib1, iw2t, ib2, iwot, ibo, tree, dOut, l, 0);
  }

  (void)in_sizes; (void)n_in; (void)out_size; (void)ws_size;
}

// Round 4
// 1191.057 us; speedup vs baseline: 1.0268x; 1.0268x over previous
//
#include <hip/hip_runtime.h>
#include <cstdint>
#include <cstddef>
#include <type_traits>

// ---------------- problem constants ----------------
#define OUT_DIM    65
#define TREE_STRIDE 66
#define N_NODE     1023
#define N_INTN     511

typedef _Float16 f16;
typedef _Float16 f16x8 __attribute__((ext_vector_type(8)));
typedef _Float16 f16x4 __attribute__((ext_vector_type(4)));
typedef float    f32x4 __attribute__((ext_vector_type(4)));

template<int V> using ic = std::integral_constant<int, V>;

#define MFMA(a, b, c) __builtin_amdgcn_mfma_f32_16x16x32_f16((a), (b), (c), 0, 0, 0)

// counted wait, compile-time immediates; "memory" clobber pins load scheduling
template<int VM, int LG>
__device__ __forceinline__ void waitcnt_t() {
  asm volatile("s_waitcnt vmcnt(%0) lgkmcnt(%1)" :: "n"(VM), "n"(LG) : "memory");
}

// H swizzle: elem(row,k) at row*512 + (((k>>3) ^ (row&15))<<3) + (k&7)
template<int MT>
__device__ __forceinline__ void storeH_fn(f16* __restrict__ H, f32x4 (&acc)[MT][4],
                                          const float* __restrict__ bias,
                                          int wcb, int quad, int l16) {
#pragma unroll
  for (int mt = 0; mt < MT; mt++) {
#pragma unroll
    for (int nt = 0; nt < 4; nt++) {
      const int c0 = wcb + nt * 16 + quad * 4;
      const float4 bv = *(const float4*)(bias + c0);
      f16x4 hv;
      float v0 = acc[mt][nt][0] + bv.x; hv[0] = (f16)(v0 > 0.f ? v0 : 0.f);
      float v1 = acc[mt][nt][1] + bv.y; hv[1] = (f16)(v1 > 0.f ? v1 : 0.f);
      float v2 = acc[mt][nt][2] + bv.z; hv[2] = (f16)(v2 > 0.f ? v2 : 0.f);
      float v3 = acc[mt][nt][3] + bv.w; hv[3] = (f16)(v3 > 0.f ? v3 : 0.f);
      const int row = mt * 16 + l16;
      *(f16x4*)&H[row * 512 + (((c0 >> 3) ^ l16) << 3) + (quad & 1) * 4] = hv;
    }
  }
}

// ---------------------------------------------------------------------------
// Barrier-free K-loop. B: global->VGPR from FRAGMENT-LINEAR weights (each
// (chunk, colblock) stores 64 lanes' 16B fragments contiguously -> one
// coalesced 1KB dwordx4 per load). A: via GetA (ds_read or global). Rings:
// BD-deep for B (covers L2 latency), AD-deep for A. Counted waits only; no
// __syncthreads inside — waves drift freely (B wave-private, A-src stable).
// ---------------------------------------------------------------------------
template<int NC, int MT, int NT, int BD, int AD, bool AGLOB, bool SWAP,
         typename GetB, typename GetA>
__device__ __forceinline__ void kloop(GetB getB, GetA getA, f32x4 (&acc)[MT][NT])
{
  f16x8 bs[BD][NT];
  f16x8 as[AD][MT];
#pragma unroll
  for (int c = 0; c < BD - 1 && c < NC; c++)
#pragma unroll
    for (int nt = 0; nt < NT; nt++) bs[c][nt] = getB(c, nt);
#pragma unroll
  for (int c = 0; c < AD - 1 && c < NC; c++)
#pragma unroll
    for (int mt = 0; mt < MT; mt++) as[c][mt] = getA(c, mt);

  auto lp = [&](auto&& self, auto Cc) -> void {
    constexpr int C = decltype(Cc)::value;
    if constexpr (C < NC) {
      if constexpr (C + BD - 1 < NC) {
#pragma unroll
        for (int nt = 0; nt < NT; nt++) bs[(C + BD - 1) % BD][nt] = getB(C + BD - 1, nt);
      }
      if constexpr (C + AD - 1 < NC) {
#pragma unroll
        for (int mt = 0; mt < MT; mt++) as[(C + AD - 1) % AD][mt] = getA(C + AD - 1, mt);
      }
      constexpr int BOUT = (BD - 1) < (NC - 1 - C) ? (BD - 1) : (NC - 1 - C);
      constexpr int AOUT = (AD - 1) < (NC - 1 - C) ? (AD - 1) : (NC - 1 - C);
      if constexpr (AGLOB) waitcnt_t<0, 0>();       // A-globals share vmcnt
      else                 waitcnt_t<NT * BOUT, MT * AOUT>();
      __builtin_amdgcn_s_setprio(1);
#pragma unroll
      for (int mt = 0; mt < MT; mt++)
#pragma unroll
        for (int nt = 0; nt < NT; nt++)
          acc[mt][nt] = SWAP ? MFMA(bs[C % BD][nt], as[C % AD][mt], acc[mt][nt])
                             : MFMA(as[C % AD][mt], bs[C % BD][nt], acc[mt][nt]);
      __builtin_amdgcn_s_setprio(0);
      self(self, ic<C + 1>{});
    }
  };
  lp(lp, ic<0>{});
}

// one 512-col layer, 128 rows (MT=8), 8 waves each owning 64 cols.
// B fragment-linear: frag(c, cb, lane) at ((c*32 + cb)*64 + lane)*8 f16.
template<int K, bool AGLOB, typename GetA>
__device__ __forceinline__ void run_layer(
    const f16* __restrict__ Wt, const float* __restrict__ bias,
    f16* __restrict__ H, int wave, int lane, int quad, int l16, GetA getA)
{
  constexpr int NC = K / 32;
  const int wcb = wave * 64;
  const f16* bbase = Wt + (long)(wave * 4) * 512 + lane * 8;
  auto getB = [&](int c, int nt) -> f16x8 {
    return *(const f16x8*)(bbase + (long)(c * 32 + nt) * 512);
  };
  f32x4 acc[8][4];
#pragma unroll
  for (int i = 0; i < 8; i++)
#pragma unroll
    for (int j = 0; j < 4; j++) acc[i][j] = f32x4{0.f, 0.f, 0.f, 0.f};

  kloop<NC, 8, 4, 2, 2, AGLOB, true>(getB, getA, acc);  // swapped: row=l16, col=quad*4+r

  __syncthreads();                 // all H/X reads of this layer done
  storeH_fn<8>(H, acc, bias, wcb, quad, l16);
  __syncthreads();                 // H visible for next layer
}

// ---------------- fused 4-layer MLP, 128 rows/block, 512 thr, any level -----
// LDS: H[128][512] f16 = 128KB. X[128][232] (internal l0 input) aliases H —
// safe: storeH(l0) writes H only after the barrier when all X reads are done.
__global__ __launch_bounds__(512, 2) void fused_mlp(
    const float* __restrict__ feats,
    const f16* __restrict__ w0t, const float* __restrict__ b0,
    const f16* __restrict__ w1t, const float* __restrict__ b1,
    const f16* __restrict__ w2t, const float* __restrict__ b2,
    const f16* __restrict__ wot, const float* __restrict__ bo,
    f16* __restrict__ tree, float* __restrict__ dOut, int lvl, int leaf)
{
  extern __shared__ f16 S[];
  f16* H = S;            // 65536 f16
  f16* X = S;            // [128][232] (internal l0 only; alias of H)

  const int tid  = threadIdx.x;
  const int wave = tid >> 6;
  const int lane = tid & 63;
  const int quad = lane >> 4;
  const int l16  = lane & 15;
  const long rowBase = (long)blockIdx.x * 128;

  if (!leaf) {
    // per-row (batch,node) mapping — valid when blocks span batch elements
    for (int i = tid; i < 8192; i += 512) {        // feats: 128 rows x 64
      int r = i >> 6, cc = i & 63;
      long rg = rowBase + r;
      long bbr = rg >> lvl;
      long ii = rg - (bbr << lvl);
      long nn = (1L << lvl) - 1 + ii;
      X[r * 232 + cc] = (f16)feats[(bbr * N_INTN + nn) * 64 + cc];
    }
    for (int i = tid; i < 16896; i += 512) {       // children: 128 rows x 132
      int r = i / 132, cc = i - r * 132;
      long rg = rowBase + r;
      long bbr = rg >> lvl;
      long ii = rg - (bbr << lvl);
      long nn = (1L << lvl) - 1 + ii;
      const f16* src = tree + (bbr * N_NODE + 2 * nn + 1) * TREE_STRIDE;
      // skip tree col 65 (uninitialized pad): left j -> k=64+j, right j -> 129+j
      int dst = (cc < 66) ? (cc == 65 ? -1 : 64 + cc)
                          : (cc == 131 ? -1 : 63 + cc);
      if (dst >= 0) X[r * 232 + dst] = src[cc];
    }
    for (int i = tid; i < 4864; i += 512) {        // zero k=194..231
      int r = i / 38, cc = i - r * 38;
      X[r * 232 + 194 + cc] = (f16)0.f;
    }
    __syncthreads();
  }

  // ---- layer 0 ----
  if (leaf) {
    auto gA = [&](int c, int mt) -> f16x8 {
      const float4* p = (const float4*)(feats + (rowBase + mt * 16 + l16) * 64 + c * 32 + quad * 8);
      float4 u0 = p[0], u1 = p[1];
      f16x8 a;
      a[0] = (f16)u0.x; a[1] = (f16)u0.y; a[2] = (f16)u0.z; a[3] = (f16)u0.w;
      a[4] = (f16)u1.x; a[5] = (f16)u1.y; a[6] = (f16)u1.z; a[7] = (f16)u1.w;
      return a;
    };
    run_layer<64, true>(w0t, b0, H, wave, lane, quad, l16, gA);
  } else {
    auto gA = [&](int c, int mt) -> f16x8 {
      int row = mt * 16 + l16;
      return *(const f16x8*)&X[row * 232 + c * 32 + quad * 8];  // max 223 < 232
    };
    run_layer<224, false>(w0t, b0, H, wave, lane, quad, l16, gA);
  }

  // ---- mid layers (A from H) ----
  auto getAH = [&](int c, int mt) -> f16x8 {
    int row = mt * 16 + l16;
    return *(const f16x8*)&H[row * 512 + ((((c * 4 + quad) ^ l16) << 3))];
  };
  run_layer<512, false>(w1t, b1, H, wave, lane, quad, l16, getAH);
  run_layer<512, false>(w2t, b2, H, wave, lane, quad, l16, getAH);

  // ---- out layer (512 -> 65), all 8 waves, 16 rows each ----
  {
    const f16* obase = wot + lane * 8;             // frag-linear, NB=5
    auto gB = [&](int c, int nt) -> f16x8 {
      return *(const f16x8*)(obase + (long)(c * 5 + nt) * 512);
    };
    const int orow = wave * 16 + l16;
    auto gA = [&](int c, int mt) -> f16x8 {
      return *(const f16x8*)&H[orow * 512 + ((((c * 4 + quad) ^ l16) << 3))];
    };
    f32x4 oacc[1][5];
#pragma unroll
    for (int i = 0; i < 5; i++) oacc[0][i] = f32x4{0.f, 0.f, 0.f, 0.f};

    kloop<16, 1, 5, 2, 2, false, false>(gB, gA, oacc);  // normal: row=quad*4+r, col=nt*16+l16

#pragma unroll
    for (int nt = 0; nt < 5; nt++)
#pragma unroll
      for (int r = 0; r < 4; r++) {
        int col = nt * 16 + l16;
        if (col < OUT_DIM) {
          long rg = rowBase + wave * 16 + quad * 4 + r;
          float v = oacc[0][nt][r] + bo[col];
          long b2_ = rg >> lvl;
          long ii  = rg - (b2_ << lvl);
          long node = (1L << lvl) - 1 + ii;
          tree[(b2_ * N_NODE + node) * TREE_STRIDE + col] = (f16)v;
          if (lvl == 0 && col == 0) dOut[rg] = v;   // lvl 0: rg = batch index
        }
      }
  }
}

// ---------------- weight repack: transpose+cast to FRAGMENT-LINEAR ----------
// elem e of a segment: j=e&7, lane=(e>>3)&63, q=e>>9, cb=q%NB, c=q/NB;
// stores W[k= c*32+(lane>>4)*8+j][col= cb*16+(lane&15)] (0-padded).
struct WSeg { const float* W; f16* Wt; int K, N, NB, start; };
struct WPack { WSeg s[8]; int total; };

__global__ void wcast_all(WPack p) {
  int idx = blockIdx.x * 256 + threadIdx.x;
  if (idx >= p.total) return;
  int si = 0;
#pragma unroll
  for (int i = 1; i < 8; i++) if (idx >= p.s[i].start) si = i;
  WSeg sg = p.s[si];
  int e = idx - sg.start;
  int j = e & 7, lane = (e >> 3) & 63, q = e >> 9;
  int cb = q % sg.NB, c = q / sg.NB;
  int col = cb * 16 + (lane & 15);
  int k = c * 32 + (lane >> 4) * 8 + j;
  float v = (col < sg.N && k < sg.K) ? sg.W[(long)k * sg.N + col] : 0.f;
  sg.Wt[e] = (f16)v;
}

// ---------------- host orchestration ----------------
extern "C" void kernel_launch(void* const* d_in, const int* in_sizes, int n_in,
                              void* d_out, int out_size, void* d_ws, size_t ws_size,
                              hipStream_t stream) {
  const float* leaf_feats     = (const float*)d_in[0];
  const float* internal_feats = (const float*)d_in[1];
  const float* lw0 = (const float*)d_in[2];
  const float* lb0 = (const float*)d_in[3];
  const float* lw1 = (const float*)d_in[4];
  const float* lb1 = (const float*)d_in[5];
  const float* lw2 = (const float*)d_in[6];
  const float* lb2 = (const float*)d_in[7];
  const float* lwo = (const float*)d_in[8];
  const float* lbo = (const float*)d_in[9];
  const float* iw0 = (const float*)d_in[10];
  const float* ib0 = (const float*)d_in[11];
  const float* iw1 = (const float*)d_in[12];
  const float* ib1 = (const float*)d_in[13];
  const float* iw2 = (const float*)d_in[14];
  const float* ib2 = (const float*)d_in[15];
  const float* iwo = (const float*)d_in[16];
  const float* ibo = (const float*)d_in[17];
  float* dOut = (float*)d_out;

  char* ws = (char*)d_ws;
  size_t off = 0;
  auto alloc = [&](size_t bytes) -> void* {
    void* p = ws + off;
    off += (bytes + 255) & ~(size_t)255;
    return p;
  };

  f16* lw0t = (f16*)alloc((size_t)64  * 512 * 2);
  f16* lw1t = (f16*)alloc((size_t)512 * 512 * 2);
  f16* lw2t = (f16*)alloc((size_t)512 * 512 * 2);
  f16* lwot = (f16*)alloc((size_t)512 * 80  * 2);
  f16* iw0t = (f16*)alloc((size_t)224 * 512 * 2);
  f16* iw1t = (f16*)alloc((size_t)512 * 512 * 2);
  f16* iw2t = (f16*)alloc((size_t)512 * 512 * 2);
  f16* iwot = (f16*)alloc((size_t)512 * 80  * 2);
  f16* tree = (f16*)alloc((size_t)256 * N_NODE * TREE_STRIDE * 2);

  WPack p;
  int cum = 0;
  auto seg = [&](int i, const float* W, f16* Wt, int K, int N, int Kpad, int NB) {
    p.s[i] = {W, Wt, K, N, NB, cum};
    cum += Kpad * NB * 16;
  };
  seg(0, lw0, lw0t, 64, 512, 64, 32);
  seg(1, lw1, lw1t, 512, 512, 512, 32);
  seg(2, lw2, lw2t, 512, 512, 512, 32);
  seg(3, lwo, lwot, 512, 65, 512, 5);
  seg(4, iw0, iw0t, 194, 512, 224, 32);
  seg(5, iw1, iw1t, 512, 512, 512, 32);
  seg(6, iw2, iw2t, 512, 512, 512, 32);
  seg(7, iwo, iwot, 512, 65, 512, 5);
  p.total = cum;
  wcast_all<<<dim3((cum + 255) / 256), dim3(256), 0, stream>>>(p);

  static bool attrSet = false;
  if (!attrSet) {
    hipFuncSetAttribute(reinterpret_cast<const void*>(fused_mlp),
                        hipFuncAttributeMaxDynamicSharedMemorySize, 131072);
    attrSet = true;
  }

  const size_t shmem = 131072;   // H 128KB (X aliased)

  // leaf pass: 131072 rows -> nodes 511..1022
  fused_mlp<<<dim3(1024), dim3(512), shmem, stream>>>(
      leaf_feats, lw0t, lb0, lw1t, lb1, lw2t, lb2, lwot, lbo, tree, dOut, 9, 1);

  // internal levels 8..0 (grid = rows/128 = 2<<l; weights stay L2-hot)
  for (int l = 8; l >= 0; l--) {
    fused_mlp<<<dim3(2u << l), dim3(512), shmem, stream>>>(
        internal_feats, iw0t, ib0, iw1t, ib1, iw2t, ib2, iwot, ibo, tree, dOut, l, 0);
  }

  (void)in_sizes; (void)n_in; (void)out_size; (void)ws_size;
}

// Round 5
// 1182.784 us; speedup vs baseline: 1.0340x; 1.0070x over previous
//
#include <hip/hip_runtime.h>
#include <cstdint>
#include <cstddef>
#include <type_traits>

// ---------------- problem constants ----------------
#define OUT_DIM    65
#define TREE_STRIDE 66
#define N_NODE     1023
#define N_INTN     511

typedef _Float16 f16;
typedef _Float16 f16x8 __attribute__((ext_vector_type(8)));
typedef _Float16 f16x4 __attribute__((ext_vector_type(4)));
typedef float    f32x4 __attribute__((ext_vector_type(4)));

template<int V> using ic = std::integral_constant<int, V>;

#define MFMA(a, b, c) __builtin_amdgcn_mfma_f32_16x16x32_f16((a), (b), (c), 0, 0, 0)

// counted wait, compile-time immediates; "memory" clobber pins load scheduling
template<int VM, int LG>
__device__ __forceinline__ void waitcnt_t() {
  asm volatile("s_waitcnt vmcnt(%0) lgkmcnt(%1)" :: "n"(VM), "n"(LG) : "memory");
}

// H swizzle: elem(row,k) at row*512 + (((k>>3) ^ (row&15))<<3) + (k&7)
template<int MT>
__device__ __forceinline__ void storeH_fn(f16* __restrict__ H, f32x4 (&acc)[MT][4],
                                          const float* __restrict__ bias,
                                          int wcb, int quad, int l16) {
#pragma unroll
  for (int mt = 0; mt < MT; mt++) {
#pragma unroll
    for (int nt = 0; nt < 4; nt++) {
      const int c0 = wcb + nt * 16 + quad * 4;
      const float4 bv = *(const float4*)(bias + c0);
      f16x4 hv;
      float v0 = acc[mt][nt][0] + bv.x; hv[0] = (f16)(v0 > 0.f ? v0 : 0.f);
      float v1 = acc[mt][nt][1] + bv.y; hv[1] = (f16)(v1 > 0.f ? v1 : 0.f);
      float v2 = acc[mt][nt][2] + bv.z; hv[2] = (f16)(v2 > 0.f ? v2 : 0.f);
      float v3 = acc[mt][nt][3] + bv.w; hv[3] = (f16)(v3 > 0.f ? v3 : 0.f);
      const int row = mt * 16 + l16;
      *(f16x4*)&H[row * 512 + (((c0 >> 3) ^ l16) << 3) + (quad & 1) * 4] = hv;
    }
  }
}

// ---------------------------------------------------------------------------
// Barrier-free K-loop. B: global->VGPR from FRAGMENT-LINEAR weights (each
// (chunk, colblock) stores 64 lanes' 16B fragments contiguously -> one
// coalesced 1KB dwordx4 per load). A: via GetA (ds_read or global). Rings:
// BD-deep for B (covers L2 latency), AD-deep for A. Counted waits only; no
// __syncthreads inside — waves drift freely (B wave-private, A-src stable).
// ---------------------------------------------------------------------------
template<int NC, int MT, int NT, int BD, int AD, bool AGLOB, bool SWAP,
         typename GetB, typename GetA>
__device__ __forceinline__ void kloop(GetB getB, GetA getA, f32x4 (&acc)[MT][NT])
{
  f16x8 bs[BD][NT];
  f16x8 as[AD][MT];
#pragma unroll
  for (int c = 0; c < BD - 1 && c < NC; c++)
#pragma unroll
    for (int nt = 0; nt < NT; nt++) bs[c][nt] = getB(c, nt);
#pragma unroll
  for (int c = 0; c < AD - 1 && c < NC; c++)
#pragma unroll
    for (int mt = 0; mt < MT; mt++) as[c][mt] = getA(c, mt);

  auto lp = [&](auto&& self, auto Cc) -> void {
    constexpr int C = decltype(Cc)::value;
    if constexpr (C < NC) {
      if constexpr (C + BD - 1 < NC) {
#pragma unroll
        for (int nt = 0; nt < NT; nt++) bs[(C + BD - 1) % BD][nt] = getB(C + BD - 1, nt);
      }
      if constexpr (C + AD - 1 < NC) {
#pragma unroll
        for (int mt = 0; mt < MT; mt++) as[(C + AD - 1) % AD][mt] = getA(C + AD - 1, mt);
      }
      constexpr int BOUT = (BD - 1) < (NC - 1 - C) ? (BD - 1) : (NC - 1 - C);
      constexpr int AOUT = (AD - 1) < (NC - 1 - C) ? (AD - 1) : (NC - 1 - C);
      if constexpr (AGLOB) waitcnt_t<0, 0>();       // A-globals share vmcnt
      else                 waitcnt_t<NT * BOUT, MT * AOUT>();
      __builtin_amdgcn_s_setprio(1);
#pragma unroll
      for (int mt = 0; mt < MT; mt++)
#pragma unroll
        for (int nt = 0; nt < NT; nt++)
          acc[mt][nt] = SWAP ? MFMA(bs[C % BD][nt], as[C % AD][mt], acc[mt][nt])
                             : MFMA(as[C % AD][mt], bs[C % BD][nt], acc[mt][nt]);
      __builtin_amdgcn_s_setprio(0);
      self(self, ic<C + 1>{});
    }
  };
  lp(lp, ic<0>{});
}

// one 512-col layer, 128 rows (MT=8), 8 waves each owning 64 cols.
// B fragment-linear: frag(c, cb, lane) at ((c*32 + cb)*64 + lane)*8 f16.
template<int K, bool AGLOB, typename GetA>
__device__ __forceinline__ void run_layer(
    const f16* __restrict__ Wt, const float* __restrict__ bias,
    f16* __restrict__ H, int wave, int lane, int quad, int l16, GetA getA)
{
  constexpr int NC = K / 32;
  const int wcb = wave * 64;
  const f16* bbase = Wt + (long)(wave * 4) * 512 + lane * 8;
  auto getB = [&](int c, int nt) -> f16x8 {
    return *(const f16x8*)(bbase + (long)(c * 32 + nt) * 512);
  };
  f32x4 acc[8][4];
#pragma unroll
  for (int i = 0; i < 8; i++)
#pragma unroll
    for (int j = 0; j < 4; j++) acc[i][j] = f32x4{0.f, 0.f, 0.f, 0.f};

  kloop<NC, 8, 4, 2, 2, AGLOB, true>(getB, getA, acc);  // swapped: row=l16, col=quad*4+r

  __syncthreads();                 // all H/X reads of this layer done
  storeH_fn<8>(H, acc, bias, wcb, quad, l16);
  __syncthreads();                 // H visible for next layer
}

// ---------------- fused 4-layer MLP, 128 rows/block, 512 thr, any level -----
// LDS: H[128][512] f16 = 128KB. X[128][232] (internal l0 input) aliases H —
// safe: storeH(l0) writes H only after the barrier when all X reads are done.
// __launch_bounds__(512, 1): VGPR cap 256 (NOT 128 — the MT=8 design needs
// ~240; at cap 128 the allocator spills ~110 regs -> 330MB scratch traffic,
// the round-4 regression).
__global__ __launch_bounds__(512, 1) void fused_mlp(
    const float* __restrict__ feats,
    const f16* __restrict__ w0t, const float* __restrict__ b0,
    const f16* __restrict__ w1t, const float* __restrict__ b1,
    const f16* __restrict__ w2t, const float* __restrict__ b2,
    const f16* __restrict__ wot, const float* __restrict__ bo,
    f16* __restrict__ tree, float* __restrict__ dOut, int lvl, int leaf)
{
  extern __shared__ f16 S[];
  f16* H = S;            // 65536 f16
  f16* X = S;            // [128][232] (internal l0 only; alias of H)

  const int tid  = threadIdx.x;
  const int wave = tid >> 6;
  const int lane = tid & 63;
  const int quad = lane >> 4;
  const int l16  = lane & 15;
  const long rowBase = (long)blockIdx.x * 128;

  if (!leaf) {
    // per-row (batch,node) mapping — valid when blocks span batch elements
    for (int i = tid; i < 8192; i += 512) {        // feats: 128 rows x 64
      int r = i >> 6, cc = i & 63;
      long rg = rowBase + r;
      long bbr = rg >> lvl;
      long ii = rg - (bbr << lvl);
      long nn = (1L << lvl) - 1 + ii;
      X[r * 232 + cc] = (f16)feats[(bbr * N_INTN + nn) * 64 + cc];
    }
    for (int i = tid; i < 16896; i += 512) {       // children: 128 rows x 132
      int r = i / 132, cc = i - r * 132;
      long rg = rowBase + r;
      long bbr = rg >> lvl;
      long ii = rg - (bbr << lvl);
      long nn = (1L << lvl) - 1 + ii;
      const f16* src = tree + (bbr * N_NODE + 2 * nn + 1) * TREE_STRIDE;
      // skip tree col 65 (uninitialized pad): left j -> k=64+j, right j -> 129+j
      int dst = (cc < 66) ? (cc == 65 ? -1 : 64 + cc)
                          : (cc == 131 ? -1 : 63 + cc);
      if (dst >= 0) X[r * 232 + dst] = src[cc];
    }
    for (int i = tid; i < 4864; i += 512) {        // zero k=194..231
      int r = i / 38, cc = i - r * 38;
      X[r * 232 + 194 + cc] = (f16)0.f;
    }
    __syncthreads();
  }

  // ---- layer 0 ----
  if (leaf) {
    auto gA = [&](int c, int mt) -> f16x8 {
      const float4* p = (const float4*)(feats + (rowBase + mt * 16 + l16) * 64 + c * 32 + quad * 8);
      float4 u0 = p[0], u1 = p[1];
      f16x8 a;
      a[0] = (f16)u0.x; a[1] = (f16)u0.y; a[2] = (f16)u0.z; a[3] = (f16)u0.w;
      a[4] = (f16)u1.x; a[5] = (f16)u1.y; a[6] = (f16)u1.z; a[7] = (f16)u1.w;
      return a;
    };
    run_layer<64, true>(w0t, b0, H, wave, lane, quad, l16, gA);
  } else {
    auto gA = [&](int c, int mt) -> f16x8 {
      int row = mt * 16 + l16;
      return *(const f16x8*)&X[row * 232 + c * 32 + quad * 8];  // max 223 < 232
    };
    run_layer<224, false>(w0t, b0, H, wave, lane, quad, l16, gA);
  }

  // ---- mid layers (A from H) ----
  auto getAH = [&](int c, int mt) -> f16x8 {
    int row = mt * 16 + l16;
    return *(const f16x8*)&H[row * 512 + ((((c * 4 + quad) ^ l16) << 3))];
  };
  run_layer<512, false>(w1t, b1, H, wave, lane, quad, l16, getAH);
  run_layer<512, false>(w2t, b2, H, wave, lane, quad, l16, getAH);

  // ---- out layer (512 -> 65), all 8 waves, 16 rows each ----
  {
    const f16* obase = wot + lane * 8;             // frag-linear, NB=5
    auto gB = [&](int c, int nt) -> f16x8 {
      return *(const f16x8*)(obase + (long)(c * 5 + nt) * 512);
    };
    const int orow = wave * 16 + l16;
    auto gA = [&](int c, int mt) -> f16x8 {
      return *(const f16x8*)&H[orow * 512 + ((((c * 4 + quad) ^ l16) << 3))];
    };
    f32x4 oacc[1][5];
#pragma unroll
    for (int i = 0; i < 5; i++) oacc[0][i] = f32x4{0.f, 0.f, 0.f, 0.f};

    kloop<16, 1, 5, 2, 2, false, false>(gB, gA, oacc);  // normal: row=quad*4+r, col=nt*16+l16

#pragma unroll
    for (int nt = 0; nt < 5; nt++)
#pragma unroll
      for (int r = 0; r < 4; r++) {
        int col = nt * 16 + l16;
        if (col < OUT_DIM) {
          long rg = rowBase + wave * 16 + quad * 4 + r;
          float v = oacc[0][nt][r] + bo[col];
          long b2_ = rg >> lvl;
          long ii  = rg - (b2_ << lvl);
          long node = (1L << lvl) - 1 + ii;
          tree[(b2_ * N_NODE + node) * TREE_STRIDE + col] = (f16)v;
          if (lvl == 0 && col == 0) dOut[rg] = v;   // lvl 0: rg = batch index
        }
      }
  }
}

// ---------------- weight repack: transpose+cast to FRAGMENT-LINEAR ----------
// elem e of a segment: j=e&7, lane=(e>>3)&63, q=e>>9, cb=q%NB, c=q/NB;
// stores W[k= c*32+(lane>>4)*8+j][col= cb*16+(lane&15)] (0-padded).
struct WSeg { const float* W; f16* Wt; int K, N, NB, start; };
struct WPack { WSeg s[8]; int total; };

__global__ void wcast_all(WPack p) {
  int idx = blockIdx.x * 256 + threadIdx.x;
  if (idx >= p.total) return;
  int si = 0;
#pragma unroll
  for (int i = 1; i < 8; i++) if (idx >= p.s[i].start) si = i;
  WSeg sg = p.s[si];
  int e = idx - sg.start;
  int j = e & 7, lane = (e >> 3) & 63, q = e >> 9;
  int cb = q % sg.NB, c = q / sg.NB;
  int col = cb * 16 + (lane & 15);
  int k = c * 32 + (lane >> 4) * 8 + j;
  float v = (col < sg.N && k < sg.K) ? sg.W[(long)k * sg.N + col] : 0.f;
  sg.Wt[e] = (f16)v;
}

// ---------------- host orchestration ----------------
extern "C" void kernel_launch(void* const* d_in, const int* in_sizes, int n_in,
                              void* d_out, int out_size, void* d_ws, size_t ws_size,
                              hipStream_t stream) {
  const float* leaf_feats     = (const float*)d_in[0];
  const float* internal_feats = (const float*)d_in[1];
  const float* lw0 = (const float*)d_in[2];
  const float* lb0 = (const float*)d_in[3];
  const float* lw1 = (const float*)d_in[4];
  const float* lb1 = (const float*)d_in[5];
  const float* lw2 = (const float*)d_in[6];
  const float* lb2 = (const float*)d_in[7];
  const float* lwo = (const float*)d_in[8];
  const float* lbo = (const float*)d_in[9];
  const float* iw0 = (const float*)d_in[10];
  const float* ib0 = (const float*)d_in[11];
  const float* iw1 = (const float*)d_in[12];
  const float* ib1 = (const float*)d_in[13];
  const float* iw2 = (const float*)d_in[14];
  const float* ib2 = (const float*)d_in[15];
  const float* iwo = (const float*)d_in[16];
  const float* ibo = (const float*)d_in[17];
  float* dOut = (float*)d_out;

  char* ws = (char*)d_ws;
  size_t off = 0;
  auto alloc = [&](size_t bytes) -> void* {
    void* p = ws + off;
    off += (bytes + 255) & ~(size_t)255;
    return p;
  };

  f16* lw0t = (f16*)alloc((size_t)64  * 512 * 2);
  f16* lw1t = (f16*)alloc((size_t)512 * 512 * 2);
  f16* lw2t = (f16*)alloc((size_t)512 * 512 * 2);
  f16* lwot = (f16*)alloc((size_t)512 * 80  * 2);
  f16* iw0t = (f16*)alloc((size_t)224 * 512 * 2);
  f16* iw1t = (f16*)alloc((size_t)512 * 512 * 2);
  f16* iw2t = (f16*)alloc((size_t)512 * 512 * 2);
  f16* iwot = (f16*)alloc((size_t)512 * 80  * 2);
  f16* tree = (f16*)alloc((size_t)256 * N_NODE * TREE_STRIDE * 2);

  WPack p;
  int cum = 0;
  auto seg = [&](int i, const float* W, f16* Wt, int K, int N, int Kpad, int NB) {
    p.s[i] = {W, Wt, K, N, NB, cum};
    cum += Kpad * NB * 16;
  };
  seg(0, lw0, lw0t, 64, 512, 64, 32);
  seg(1, lw1, lw1t, 512, 512, 512, 32);
  seg(2, lw2, lw2t, 512, 512, 512, 32);
  seg(3, lwo, lwot, 512, 65, 512, 5);
  seg(4, iw0, iw0t, 194, 512, 224, 32);
  seg(5, iw1, iw1t, 512, 512, 512, 32);
  seg(6, iw2, iw2t, 512, 512, 512, 32);
  seg(7, iwo, iwot, 512, 65, 512, 5);
  p.total = cum;
  wcast_all<<<dim3((cum + 255) / 256), dim3(256), 0, stream>>>(p);

  static bool attrSet = false;
  if (!attrSet) {
    hipFuncSetAttribute(reinterpret_cast<const void*>(fused_mlp),
                        hipFuncAttributeMaxDynamicSharedMemorySize, 131072);
    attrSet = true;
  }

  const size_t shmem = 131072;   // H 128KB (X aliased)

  // leaf pass: 131072 rows -> nodes 511..1022
  fused_mlp<<<dim3(1024), dim3(512), shmem, stream>>>(
      leaf_feats, lw0t, lb0, lw1t, lb1, lw2t, lb2, lwot, lbo, tree, dOut, 9, 1);

  // internal levels 8..0 (grid = rows/128 = 2<<l; weights stay L2-hot)
  for (int l = 8; l >= 0; l--) {
    fused_mlp<<<dim3(2u << l), dim3(512), shmem, stream>>>(
        internal_feats, iw0t, ib0, iw1t, ib1, iw2t, ib2, iwot, ibo, tree, dOut, l, 0);
  }

  (void)in_sizes; (void)n_in; (void)out_size; (void)ws_size;
}

// Round 6
// 681.742 us; speedup vs baseline: 1.7939x; 1.7349x over previous
//
#include <hip/hip_runtime.h>
#include <cstdint>
#include <cstddef>
#include <type_traits>

// ---------------- problem constants ----------------
#define OUT_DIM    65
#define TREE_STRIDE 66
#define N_NODE     1023
#define N_INTN     511

typedef _Float16 f16;
typedef _Float16 f16x8 __attribute__((ext_vector_type(8)));
typedef _Float16 f16x4 __attribute__((ext_vector_type(4)));
typedef float    f32x4 __attribute__((ext_vector_type(4)));

template<int V> using ic = std::integral_constant<int, V>;

#define MFMA(a, b, c) __builtin_amdgcn_mfma_f32_16x16x32_f16((a), (b), (c), 0, 0, 0)

// counted wait, compile-time immediates; "memory" clobber pins load scheduling
template<int VM, int LG>
__device__ __forceinline__ void waitcnt_t() {
  asm volatile("s_waitcnt vmcnt(%0) lgkmcnt(%1)" :: "n"(VM), "n"(LG) : "memory");
}

// H swizzle: elem(row,k) at row*512 + (((k>>3) ^ (row&15))<<3) + (k&7)
template<int MT>
__device__ __forceinline__ void storeH_fn(f16* __restrict__ H, f32x4 (&acc)[MT][4],
                                          const float* __restrict__ bias,
                                          int wcb, int quad, int l16) {
#pragma unroll
  for (int mt = 0; mt < MT; mt++) {
#pragma unroll
    for (int nt = 0; nt < 4; nt++) {
      const int c0 = wcb + nt * 16 + quad * 4;
      const float4 bv = *(const float4*)(bias + c0);
      f16x4 hv;
      float v0 = acc[mt][nt][0] + bv.x; hv[0] = (f16)(v0 > 0.f ? v0 : 0.f);
      float v1 = acc[mt][nt][1] + bv.y; hv[1] = (f16)(v1 > 0.f ? v1 : 0.f);
      float v2 = acc[mt][nt][2] + bv.z; hv[2] = (f16)(v2 > 0.f ? v2 : 0.f);
      float v3 = acc[mt][nt][3] + bv.w; hv[3] = (f16)(v3 > 0.f ? v3 : 0.f);
      const int row = mt * 16 + l16;
      *(f16x4*)&H[row * 512 + (((c0 >> 3) ^ l16) << 3) + (quad & 1) * 4] = hv;
    }
  }
}

// ---------------------------------------------------------------------------
// Barrier-free K-loop. B: global->VGPR from FRAGMENT-LINEAR weights (each
// (chunk, colblock) stores 64 lanes' 16B fragments contiguously -> one
// coalesced 1KB dwordx4 per load). A: via GetA (ds_read or global). Rings:
// BD-deep for B (covers L2 latency), AD-deep for A. Counted waits only; no
// __syncthreads inside — waves drift freely (B wave-private, A-src stable).
// ---------------------------------------------------------------------------
template<int NC, int MT, int NT, int BD, int AD, bool AGLOB, bool SWAP,
         typename GetB, typename GetA>
__device__ __forceinline__ void kloop(GetB getB, GetA getA, f32x4 (&acc)[MT][NT])
{
  f16x8 bs[BD][NT];
  f16x8 as[AD][MT];
#pragma unroll
  for (int c = 0; c < BD - 1 && c < NC; c++)
#pragma unroll
    for (int nt = 0; nt < NT; nt++) bs[c][nt] = getB(c, nt);
#pragma unroll
  for (int c = 0; c < AD - 1 && c < NC; c++)
#pragma unroll
    for (int mt = 0; mt < MT; mt++) as[c][mt] = getA(c, mt);

  auto lp = [&](auto&& self, auto Cc) -> void {
    constexpr int C = decltype(Cc)::value;
    if constexpr (C < NC) {
      if constexpr (C + BD - 1 < NC) {
#pragma unroll
        for (int nt = 0; nt < NT; nt++) bs[(C + BD - 1) % BD][nt] = getB(C + BD - 1, nt);
      }
      if constexpr (C + AD - 1 < NC) {
#pragma unroll
        for (int mt = 0; mt < MT; mt++) as[(C + AD - 1) % AD][mt] = getA(C + AD - 1, mt);
      }
      constexpr int BOUT = (BD - 1) < (NC - 1 - C) ? (BD - 1) : (NC - 1 - C);
      constexpr int AOUT = (AD - 1) < (NC - 1 - C) ? (AD - 1) : (NC - 1 - C);
      if constexpr (AGLOB) waitcnt_t<0, 0>();       // A-globals share vmcnt
      else                 waitcnt_t<NT * BOUT, MT * AOUT>();
      __builtin_amdgcn_s_setprio(1);
#pragma unroll
      for (int mt = 0; mt < MT; mt++)
#pragma unroll
        for (int nt = 0; nt < NT; nt++)
          acc[mt][nt] = SWAP ? MFMA(bs[C % BD][nt], as[C % AD][mt], acc[mt][nt])
                             : MFMA(as[C % AD][mt], bs[C % BD][nt], acc[mt][nt]);
      __builtin_amdgcn_s_setprio(0);
      self(self, ic<C + 1>{});
    }
  };
  lp(lp, ic<0>{});
}

// one 512-col layer, 64 rows (MT=4), 8 waves each owning 64 cols.
// B fragment-linear: frag(c, cb, lane) at ((c*32 + cb)*64 + lane)*8 f16,
// cb = wave*4 + nt. MT=4 keeps acc=64 VGPR -> total ~124, no spill (the
// MT=8 variant needs ~190 and the allocator hard-caps at 128 -> 330MB
// scratch traffic; rounds 4/5).
template<int K, bool AGLOB, typename GetA>
__device__ __forceinline__ void run_layer(
    const f16* __restrict__ Wt, const float* __restrict__ bias,
    f16* __restrict__ H, int wave, int lane, int quad, int l16, GetA getA)
{
  constexpr int NC = K / 32;
  const int wcb = wave * 64;
  const f16* bbase = Wt + (long)(wave * 4) * 512 + lane * 8;
  auto getB = [&](int c, int nt) -> f16x8 {
    return *(const f16x8*)(bbase + (long)(c * 32 + nt) * 512);
  };
  f32x4 acc[4][4];
#pragma unroll
  for (int i = 0; i < 4; i++)
#pragma unroll
    for (int j = 0; j < 4; j++) acc[i][j] = f32x4{0.f, 0.f, 0.f, 0.f};

  kloop<NC, 4, 4, 3, 2, AGLOB, true>(getB, getA, acc);  // swapped: row=l16, col=quad*4+r

  __syncthreads();                 // all H/X reads of this layer done
  storeH_fn<4>(H, acc, bias, wcb, quad, l16);
  __syncthreads();                 // H visible for next layer
}

// ---------------- fused 4-layer MLP, 64 rows/block, 512 thr, any level ------
// LDS: H[64][512] f16 = 64KB -> 2 blocks/CU co-resident at VGPR<=128.
// X[64][232] (internal l0 input) aliases H — safe: storeH(l0) writes H only
// after the barrier when all X reads are done.
__global__ __launch_bounds__(512, 2) void fused_mlp(
    const float* __restrict__ feats,
    const f16* __restrict__ w0t, const float* __restrict__ b0,
    const f16* __restrict__ w1t, const float* __restrict__ b1,
    const f16* __restrict__ w2t, const float* __restrict__ b2,
    const f16* __restrict__ wot, const float* __restrict__ bo,
    f16* __restrict__ tree, float* __restrict__ dOut, int lvl, int leaf)
{
  extern __shared__ f16 S[];
  f16* H = S;            // 32768 f16
  f16* X = S;            // [64][232] (internal l0 only; alias of H)

  const int tid  = threadIdx.x;
  const int wave = tid >> 6;
  const int lane = tid & 63;
  const int quad = lane >> 4;
  const int l16  = lane & 15;
  const long rowBase = (long)blockIdx.x * 64;

  if (!leaf) {
    // per-row (batch,node) mapping — valid when blocks span batch elements
    for (int i = tid; i < 4096; i += 512) {        // feats: 64 rows x 64
      int r = i >> 6, cc = i & 63;
      long rg = rowBase + r;
      long bbr = rg >> lvl;
      long ii = rg - (bbr << lvl);
      long nn = (1L << lvl) - 1 + ii;
      X[r * 232 + cc] = (f16)feats[(bbr * N_INTN + nn) * 64 + cc];
    }
    for (int i = tid; i < 8448; i += 512) {        // children: 64 rows x 132
      int r = i / 132, cc = i - r * 132;
      long rg = rowBase + r;
      long bbr = rg >> lvl;
      long ii = rg - (bbr << lvl);
      long nn = (1L << lvl) - 1 + ii;
      const f16* src = tree + (bbr * N_NODE + 2 * nn + 1) * TREE_STRIDE;
      // skip tree col 65 (uninitialized pad): left j -> k=64+j, right j -> 129+j
      int dst = (cc < 66) ? (cc == 65 ? -1 : 64 + cc)
                          : (cc == 131 ? -1 : 63 + cc);
      if (dst >= 0) X[r * 232 + dst] = src[cc];
    }
    for (int i = tid; i < 2432; i += 512) {        // zero k=194..231
      int r = i / 38, cc = i - r * 38;
      X[r * 232 + 194 + cc] = (f16)0.f;
    }
    __syncthreads();
  }

  // ---- layer 0 ----
  if (leaf) {
    auto gA = [&](int c, int mt) -> f16x8 {
      const float4* p = (const float4*)(feats + (rowBase + mt * 16 + l16) * 64 + c * 32 + quad * 8);
      float4 u0 = p[0], u1 = p[1];
      f16x8 a;
      a[0] = (f16)u0.x; a[1] = (f16)u0.y; a[2] = (f16)u0.z; a[3] = (f16)u0.w;
      a[4] = (f16)u1.x; a[5] = (f16)u1.y; a[6] = (f16)u1.z; a[7] = (f16)u1.w;
      return a;
    };
    run_layer<64, true>(w0t, b0, H, wave, lane, quad, l16, gA);
  } else {
    auto gA = [&](int c, int mt) -> f16x8 {
      int row = mt * 16 + l16;
      return *(const f16x8*)&X[row * 232 + c * 32 + quad * 8];  // max 223 < 232
    };
    run_layer<224, false>(w0t, b0, H, wave, lane, quad, l16, gA);
  }

  // ---- mid layers (A from H) ----
  auto getAH = [&](int c, int mt) -> f16x8 {
    int row = mt * 16 + l16;
    return *(const f16x8*)&H[row * 512 + ((((c * 4 + quad) ^ l16) << 3))];
  };
  run_layer<512, false>(w1t, b1, H, wave, lane, quad, l16, getAH);
  run_layer<512, false>(w2t, b2, H, wave, lane, quad, l16, getAH);

  // ---- out layer (512 -> 65), waves 0..3 compute 16 rows each ----
  if (wave < 4) {
    const f16* obase = wot + lane * 8;             // frag-linear, NB=5
    auto gB = [&](int c, int nt) -> f16x8 {
      return *(const f16x8*)(obase + (long)(c * 5 + nt) * 512);
    };
    const int orow = wave * 16 + l16;
    auto gA = [&](int c, int mt) -> f16x8 {
      return *(const f16x8*)&H[orow * 512 + ((((c * 4 + quad) ^ l16) << 3))];
    };
    f32x4 oacc[1][5];
#pragma unroll
    for (int i = 0; i < 5; i++) oacc[0][i] = f32x4{0.f, 0.f, 0.f, 0.f};

    kloop<16, 1, 5, 3, 2, false, false>(gB, gA, oacc);  // normal: row=quad*4+r, col=nt*16+l16

#pragma unroll
    for (int nt = 0; nt < 5; nt++)
#pragma unroll
      for (int r = 0; r < 4; r++) {
        int col = nt * 16 + l16;
        if (col < OUT_DIM) {
          long rg = rowBase + wave * 16 + quad * 4 + r;
          float v = oacc[0][nt][r] + bo[col];
          long b2_ = rg >> lvl;
          long ii  = rg - (b2_ << lvl);
          long node = (1L << lvl) - 1 + ii;
          tree[(b2_ * N_NODE + node) * TREE_STRIDE + col] = (f16)v;
          if (lvl == 0 && col == 0) dOut[rg] = v;   // lvl 0: rg = batch index
        }
      }
  }
}

// ---------------- weight repack: transpose+cast to FRAGMENT-LINEAR ----------
// elem e of a segment: j=e&7, lane=(e>>3)&63, q=e>>9, cb=q%NB, c=q/NB;
// stores W[k= c*32+(lane>>4)*8+j][col= cb*16+(lane&15)] (0-padded).
struct WSeg { const float* W; f16* Wt; int K, N, NB, start; };
struct WPack { WSeg s[8]; int total; };

__global__ void wcast_all(WPack p) {
  int idx = blockIdx.x * 256 + threadIdx.x;
  if (idx >= p.total) return;
  int si = 0;
#pragma unroll
  for (int i = 1; i < 8; i++) if (idx >= p.s[i].start) si = i;
  WSeg sg = p.s[si];
  int e = idx - sg.start;
  int j = e & 7, lane = (e >> 3) & 63, q = e >> 9;
  int cb = q % sg.NB, c = q / sg.NB;
  int col = cb * 16 + (lane & 15);
  int k = c * 32 + (lane >> 4) * 8 + j;
  float v = (col < sg.N && k < sg.K) ? sg.W[(long)k * sg.N + col] : 0.f;
  sg.Wt[e] = (f16)v;
}

// ---------------- host orchestration ----------------
extern "C" void kernel_launch(void* const* d_in, const int* in_sizes, int n_in,
                              void* d_out, int out_size, void* d_ws, size_t ws_size,
                              hipStream_t stream) {
  const float* leaf_feats     = (const float*)d_in[0];
  const float* internal_feats = (const float*)d_in[1];
  const float* lw0 = (const float*)d_in[2];
  const float* lb0 = (const float*)d_in[3];
  const float* lw1 = (const float*)d_in[4];
  const float* lb1 = (const float*)d_in[5];
  const float* lw2 = (const float*)d_in[6];
  const float* lb2 = (const float*)d_in[7];
  const float* lwo = (const float*)d_in[8];
  const float* lbo = (const float*)d_in[9];
  const float* iw0 = (const float*)d_in[10];
  const float* ib0 = (const float*)d_in[11];
  const float* iw1 = (const float*)d_in[12];
  const float* ib1 = (const float*)d_in[13];
  const float* iw2 = (const float*)d_in[14];
  const float* ib2 = (const float*)d_in[15];
  const float* iwo = (const float*)d_in[16];
  const float* ibo = (const float*)d_in[17];
  float* dOut = (float*)d_out;

  char* ws = (char*)d_ws;
  size_t off = 0;
  auto alloc = [&](size_t bytes) -> void* {
    void* p = ws + off;
    off += (bytes + 255) & ~(size_t)255;
    return p;
  };

  f16* lw0t = (f16*)alloc((size_t)64  * 512 * 2);
  f16* lw1t = (f16*)alloc((size_t)512 * 512 * 2);
  f16* lw2t = (f16*)alloc((size_t)512 * 512 * 2);
  f16* lwot = (f16*)alloc((size_t)512 * 80  * 2);
  f16* iw0t = (f16*)alloc((size_t)224 * 512 * 2);
  f16* iw1t = (f16*)alloc((size_t)512 * 512 * 2);
  f16* iw2t = (f16*)alloc((size_t)512 * 512 * 2);
  f16* iwot = (f16*)alloc((size_t)512 * 80  * 2);
  f16* tree = (f16*)alloc((size_t)256 * N_NODE * TREE_STRIDE * 2);

  WPack p;
  int cum = 0;
  auto seg = [&](int i, const float* W, f16* Wt, int K, int N, int Kpad, int NB) {
    p.s[i] = {W, Wt, K, N, NB, cum};
    cum += Kpad * NB * 16;
  };
  seg(0, lw0, lw0t, 64, 512, 64, 32);
  seg(1, lw1, lw1t, 512, 512, 512, 32);
  seg(2, lw2, lw2t, 512, 512, 512, 32);
  seg(3, lwo, lwot, 512, 65, 512, 5);
  seg(4, iw0, iw0t, 194, 512, 224, 32);
  seg(5, iw1, iw1t, 512, 512, 512, 32);
  seg(6, iw2, iw2t, 512, 512, 512, 32);
  seg(7, iwo, iwot, 512, 65, 512, 5);
  p.total = cum;
  wcast_all<<<dim3((cum + 255) / 256), dim3(256), 0, stream>>>(p);

  static bool attrSet = false;
  if (!attrSet) {
    hipFuncSetAttribute(reinterpret_cast<const void*>(fused_mlp),
                        hipFuncAttributeMaxDynamicSharedMemorySize, 65536);
    attrSet = true;
  }

  const size_t shmem = 65536;   // H 64KB (X aliased) -> 2 blocks/CU

  // leaf pass: 131072 rows -> nodes 511..1022
  fused_mlp<<<dim3(2048), dim3(512), shmem, stream>>>(
      leaf_feats, lw0t, lb0, lw1t, lb1, lw2t, lb2, lwot, lbo, tree, dOut, 9, 1);

  // internal levels 8..0 (grid = rows/64 = 4<<l; weights stay L2-hot)
  for (int l = 8; l >= 0; l--) {
    fused_mlp<<<dim3(4u << l), dim3(512), shmem, stream>>>(
        internal_feats, iw0t, ib0, iw1t, ib1, iw2t, ib2, iwot, ibo, tree, dOut, l, 0);
  }

  (void)in_sizes; (void)n_in; (void)out_size; (void)ws_size;
}